// Round 5
// baseline (267.596 us; speedup 1.0000x reference)
//
#include <hip/hip_runtime.h>
#include <hip/hip_bf16.h>
#include <cstdint>
#include <cstddef>

// Problem constants
#define S_LEN 2048
#define DMODEL 2048
#define NHEADS 8
#define DHEAD 128
#define INNER_DIM 1024
#define BATCH 2

typedef __bf16 bf16;
typedef __bf16 bf16x8 __attribute__((ext_vector_type(8)));
typedef __bf16 bf16x4 __attribute__((ext_vector_type(4)));
typedef float f32x4 __attribute__((ext_vector_type(4)));

#define VMCNT(n) asm volatile("s_waitcnt vmcnt(" #n ")" ::: "memory")
#define BAR()                                \
  do {                                       \
    asm volatile("" ::: "memory");           \
    __builtin_amdgcn_s_barrier();            \
    asm volatile("" ::: "memory");           \
  } while (0)

__device__ __forceinline__ void gload_lds16(const void* g, void* l) {
  __builtin_amdgcn_global_load_lds(
      (const __attribute__((address_space(1))) void*)g,
      (__attribute__((address_space(3))) void*)l, 16, 0, 0);
}

__device__ __forceinline__ float sigmoidf_(float x) {
  return 1.0f / (1.0f + expf(-x));
}

// ---------------------------------------------------------------------------
// Fused prep kernel, range-dispatched on blockIdx.x:
//   [0, 8192)     : fp32 -> bf16 weight conversion (Wq,Wk,Wv -> wqkvb; Wo -> wob)
//   [8192, 9216)  : beta[n,h] = sigmoid(x.Wb^T + bb) + xb = bf16(x); 4 rows/block
//   [9216, 9728)  : RoPE cos/sin table cs[s*64+j] (identical math to old rope)
//   [9728, 9736)  : per-head alpha (la_mean, la_d); wave 0 only
// ---------------------------------------------------------------------------
__global__ __launch_bounds__(256) void prep_kernel(
    const float* __restrict__ x, const float* __restrict__ wq,
    const float* __restrict__ wk, const float* __restrict__ wv,
    const float* __restrict__ wo, const float* __restrict__ Wb,
    const float* __restrict__ bbias, const float* __restrict__ alpha_log,
    bf16* __restrict__ wqkvb, bf16* __restrict__ wob, bf16* __restrict__ xb,
    float* __restrict__ beta, float* __restrict__ la_mean,
    float* __restrict__ la_d, float2* __restrict__ cs) {
  const int bid = blockIdx.x;
  const int tid = threadIdx.x;

  if (bid < 8192) {
    // ---- weight conversion ----
    size_t i4 = ((size_t)bid * 256 + tid) * 4;
    const float* src;
    bf16* dst;
    size_t off;
    if (i4 < 2097152UL)       { src = wq; dst = wqkvb;           off = i4; }
    else if (i4 < 4194304UL)  { src = wk; dst = wqkvb + 2097152; off = i4 - 2097152UL; }
    else if (i4 < 6291456UL)  { src = wv; dst = wqkvb + 4194304; off = i4 - 4194304UL; }
    else                      { src = wo; dst = wob;             off = i4 - 6291456UL; }
    float4 v = *(const float4*)(src + off);
    bf16x4 o;
    o[0] = (bf16)v.x; o[1] = (bf16)v.y; o[2] = (bf16)v.z; o[3] = (bf16)v.w;
    *(bf16x4*)(dst + off) = o;
  } else if (bid < 9216) {
    // ---- beta + xb: one row per wave ----
    const int n = (bid - 8192) * 4 + (tid >> 6);
    const int lane = tid & 63;
    float acc[8];
#pragma unroll
    for (int h = 0; h < 8; h++) acc[h] = 0.0f;
    const float4* x4 = (const float4*)(x + (size_t)n * DMODEL);
    bf16* xbr = xb + (size_t)n * DMODEL;
    for (int d4 = lane; d4 < DMODEL / 4; d4 += 64) {
      float4 xv = x4[d4];
      bf16x4 o;
      o[0] = (bf16)xv.x; o[1] = (bf16)xv.y; o[2] = (bf16)xv.z; o[3] = (bf16)xv.w;
      *(bf16x4*)(xbr + d4 * 4) = o;
#pragma unroll
      for (int h = 0; h < 8; h++) {
        float4 wv2 = ((const float4*)(Wb + (size_t)h * DMODEL))[d4];
        acc[h] += xv.x * wv2.x + xv.y * wv2.y + xv.z * wv2.z + xv.w * wv2.w;
      }
    }
#pragma unroll
    for (int off = 32; off; off >>= 1)
#pragma unroll
      for (int h = 0; h < 8; h++) acc[h] += __shfl_down(acc[h], off);
    if (lane == 0) {
#pragma unroll
      for (int h = 0; h < 8; h++)
        beta[(size_t)n * 8 + h] = sigmoidf_(acc[h] + bbias[h]);
    }
  } else if (bid < 9728) {
    // ---- RoPE table ----
    int idx = (bid - 9216) * 256 + tid;  // < 131072 = 2048*64
    int s = idx >> 6, j = idx & 63;
    float f = (float)s * expf(-(float)j * (9.210340371976184f / 64.0f));
    float sn, c;
    sincosf(f, &sn, &c);
    cs[idx] = make_float2(c, sn);
  } else {
    // ---- alpha (wave 0 only) ----
    if (tid >= 64) return;
    const int h = bid - 9728;
    const int lane = tid;
    float a1 = sigmoidf_(alpha_log[h * 128 + lane]);
    float a2 = sigmoidf_(alpha_log[h * 128 + 64 + lane]);
    la_d[h * 128 + lane] = logf(a1);
    la_d[h * 128 + 64 + lane] = logf(a2);
    float s = a1 + a2;
    for (int off = 32; off; off >>= 1) s += __shfl_down(s, off);
    if (lane == 0) la_mean[h] = logf(fmaxf(s * (1.0f / 128.0f), 1e-6f));
  }
}

// ---------------------------------------------------------------------------
// QKV projection: 128x384-tile 4-phase bf16 GEMM, FULL-FILL grid (256 blocks
// = 32 m-tiles x 8 n-panels, one n-panel per XCD). Unchanged from round 4.
// ---------------------------------------------------------------------------
#define QKV_K 2048
#define QKV_NT 32  // K / 64

__global__ __launch_bounds__(512, 2) void qkv_gemm8p_kernel(
    const bf16* __restrict__ A, const bf16* __restrict__ Bm,
    bf16* __restrict__ C, bf16* __restrict__ vt) {
  __shared__ __align__(16) bf16 smem[2][32768];  // buf: A[0,8192) B[8192,32768)

  const int id = blockIdx.x;
  const int wg = (id & 7) * 32 + (id >> 3);
  const int tile_n = (wg >> 5) * 384;
  const int tile_m = (wg & 31) * 128;

  const int tid = threadIdx.x;
  const int lane = tid & 63;
  const int w = tid >> 6;
  const int wm = w >> 2;  // 0..1 -> rows wm*64
  const int wn = w & 3;   // 0..3 -> cols wn*96
  const int lr = lane & 15;
  const int kq = lane >> 4;

  const int srow = lane >> 3;
  const int slot = lane & 7;
  const int sgo = (slot ^ srow) * 8;
  const int rloc = w * 8 + srow;

  size_t Aoff[2], Boff[6];
#pragma unroll
  for (int a = 0; a < 2; ++a)
    Aoff[a] = (size_t)(tile_m + a * 64 + rloc) * QKV_K + sgo;
#pragma unroll
  for (int b = 0; b < 6; ++b) {
    const int ldsr = b * 64 + rloc;
    const int qn = ldsr >= 192 ? 1 : 0;
    const int rem = ldsr - qn * 192;
    const int wng = rem / 48;
    const int rr = rem - wng * 48;
    const int gcol = wng * 96 + qn * 48 + rr;
    Boff[b] = (size_t)(tile_n + gcol) * QKV_K + sgo;
  }

  f32x4 acc[4][6];
#pragma unroll
  for (int i = 0; i < 4; i++)
#pragma unroll
    for (int j = 0; j < 6; j++) acc[i][j] = (f32x4){0.f, 0.f, 0.f, 0.f};

  auto stageAA = [&](int buf, int k0) {
#pragma unroll
    for (int a = 0; a < 2; ++a)
      gload_lds16(A + Aoff[a] + k0, &smem[buf][(a * 64 + w * 8) * 64]);
  };
  auto stageB2 = [&](int buf, int k0, int b0) {
#pragma unroll
    for (int u = 0; u < 2; ++u)
      gload_lds16(Bm + Boff[b0 + u] + k0,
                  &smem[buf][8192 + ((b0 + u) * 64 + w * 8) * 64]);
  };

  stageAA(0, 0);
  stageB2(0, 0, 0);
  stageB2(0, 0, 2);
  stageB2(0, 0, 4);
  stageAA(1, 64);
  VMCNT(5);
  BAR();

  for (int t = 0; t < QKV_NT; ++t) {
    const int buf = t & 1;
    const int k0n = (t + 1) * 64;
    const bool h1 = (t + 1 < QKV_NT);
    const bool h2 = (t + 2 < QKV_NT);
    const bf16* ldsA = smem[buf];
    const bf16* ldsB = smem[buf] + 8192;

    bf16x8 af[2][2], b0f[3][2], b1f[3][2];

    // ---- p0 ----
#pragma unroll
    for (int mi = 0; mi < 2; ++mi)
#pragma unroll
      for (int ks = 0; ks < 2; ++ks)
        af[mi][ks] = *(const bf16x8*)&ldsA[(wm * 64 + mi * 16 + lr) * 64 +
                                           (((ks * 4 + kq) ^ (lr & 7)) * 8)];
#pragma unroll
    for (int ni = 0; ni < 3; ++ni)
#pragma unroll
      for (int ks = 0; ks < 2; ++ks)
        b0f[ni][ks] = *(const bf16x8*)&ldsB[(wn * 48 + ni * 16 + lr) * 64 +
                                            (((ks * 4 + kq) ^ (lr & 7)) * 8)];
    if (h1) stageB2(buf ^ 1, k0n, 0);
    BAR();
    __builtin_amdgcn_s_setprio(1);
#pragma unroll
    for (int mi = 0; mi < 2; ++mi)
#pragma unroll
      for (int ni = 0; ni < 3; ++ni)
#pragma unroll
        for (int ks = 0; ks < 2; ++ks)
          acc[mi][ni] = __builtin_amdgcn_mfma_f32_16x16x32_bf16(
              af[mi][ks], b0f[ni][ks], acc[mi][ni], 0, 0, 0);
    __builtin_amdgcn_s_setprio(0);
    if (h1) VMCNT(4);
    else VMCNT(0);
    BAR();

    // ---- p1 ----
#pragma unroll
    for (int ni = 0; ni < 3; ++ni)
#pragma unroll
      for (int ks = 0; ks < 2; ++ks)
        b1f[ni][ks] = *(const bf16x8*)&ldsB[(192 + wn * 48 + ni * 16 + lr) * 64 +
                                            (((ks * 4 + kq) ^ (lr & 7)) * 8)];
    if (h1) stageB2(buf ^ 1, k0n, 2);
    BAR();
    __builtin_amdgcn_s_setprio(1);
#pragma unroll
    for (int mi = 0; mi < 2; ++mi)
#pragma unroll
      for (int ni = 0; ni < 3; ++ni)
#pragma unroll
        for (int ks = 0; ks < 2; ++ks)
          acc[mi][3 + ni] = __builtin_amdgcn_mfma_f32_16x16x32_bf16(
              af[mi][ks], b1f[ni][ks], acc[mi][3 + ni], 0, 0, 0);
    __builtin_amdgcn_s_setprio(0);
    BAR();

    // ---- p2 ----
#pragma unroll
    for (int mi = 0; mi < 2; ++mi)
#pragma unroll
      for (int ks = 0; ks < 2; ++ks)
        af[mi][ks] = *(const bf16x8*)&ldsA[(wm * 64 + 32 + mi * 16 + lr) * 64 +
                                           (((ks * 4 + kq) ^ (lr & 7)) * 8)];
    if (h1) stageB2(buf ^ 1, k0n, 4);
    BAR();
    __builtin_amdgcn_s_setprio(1);
#pragma unroll
    for (int mi = 0; mi < 2; ++mi)
#pragma unroll
      for (int ni = 0; ni < 3; ++ni)
#pragma unroll
        for (int ks = 0; ks < 2; ++ks)
          acc[2 + mi][3 + ni] = __builtin_amdgcn_mfma_f32_16x16x32_bf16(
              af[mi][ks], b1f[ni][ks], acc[2 + mi][3 + ni], 0, 0, 0);
    __builtin_amdgcn_s_setprio(0);
    BAR();

    // ---- p3 ----
    if (h2) stageAA(buf, (t + 2) * 64);
    BAR();
    __builtin_amdgcn_s_setprio(1);
#pragma unroll
    for (int mi = 0; mi < 2; ++mi)
#pragma unroll
      for (int ni = 0; ni < 3; ++ni)
#pragma unroll
        for (int ks = 0; ks < 2; ++ks)
          acc[2 + mi][ni] = __builtin_amdgcn_mfma_f32_16x16x32_bf16(
              af[mi][ks], b0f[ni][ks], acc[2 + mi][ni], 0, 0, 0);
    __builtin_amdgcn_s_setprio(0);
    if (h1) {
      if (h2) VMCNT(5);
      else VMCNT(3);
    }
    BAR();
  }

  const int rb = kq * 4;
#pragma unroll
  for (int mi = 0; mi < 4; ++mi) {
    const int row0 = tile_m + wm * 64 + mi * 16 + rb;
#pragma unroll
    for (int ni = 0; ni < 6; ++ni) {
      const int col = tile_n + wn * 96 + ni * 16 + lr;
      const int z = col >> 10;
      const int cz = col & 1023;
      bf16* Cz = C + (size_t)z * 4194304UL;
#pragma unroll
      for (int r2 = 0; r2 < 4; ++r2)
        Cz[(size_t)(row0 + r2) * 1024 + cz] = (bf16)acc[mi][ni][r2];
      if (z == 2) {
        const int bb2 = row0 >> 11;
        const int ss = row0 & 2047;
        bf16x4 o4;
#pragma unroll
        for (int r2 = 0; r2 < 4; ++r2) o4[r2] = (bf16)acc[mi][ni][r2];
        *(bf16x4*)&vt[(((size_t)bb2 * 8 + (cz >> 7)) * 128 + (cz & 127)) * 2048 +
                      ss] = o4;
      }
    }
  }
}

// ---------------------------------------------------------------------------
// Output projection: 128x256-tile 4-phase bf16 GEMM -> fp32 C, full-fill
// grid (256 blocks = 32 m x 8 n, one n-tile per XCD; 512KB B-panel in L2).
// Same schedule skeleton as QKV: 8 waves (2Mx4N), per-wave 64x64 (acc[4][4]),
// 8 MFMA/phase, phase walk 00->01->11->10 with held fragments.
// Stage ops (8KB = 64 rows): A:2, B:4 per K-tile. B LDS rows permuted
// (qn,wn,nf)-major: lds_row = qn*128 + wn*32 + nf*16 + r16.
// Per tile t: p0 stages B0,B1(t+1); p1: B2,B3(t+1); p2: none; p3: A(t+2)
// into CURRENT buf. vmcnt ledger (verified steady/prologue/tails):
//   end p0: VMCNT(4) (last tile: VMCNT(0)) -> drains B23(t)
//   end p3: VMCNT(4) (t=NT-2: VMCNT(2))    -> drains A(t+1),B01(t+1)
// Min load age 3 phases. Same XOR-16B-granule swizzle, linear LDS dest.
// ---------------------------------------------------------------------------
#define OP_K 1024
#define OP_NT 16  // K / 64

__global__ __launch_bounds__(512, 2) void oproj_kernel(
    const bf16* __restrict__ A, const bf16* __restrict__ Bm,
    float* __restrict__ C) {
  __shared__ __align__(16) bf16 smem[2][24576];  // A[0,8192) B[8192,24576)

  const int id = blockIdx.x;
  const int wg = (id & 7) * 32 + (id >> 3);
  const int tile_n = (wg >> 5) * 256;
  const int tile_m = (wg & 31) * 128;

  const int tid = threadIdx.x;
  const int lane = tid & 63;
  const int w = tid >> 6;
  const int wm = w >> 2;  // 0..1
  const int wn = w & 3;   // 0..3
  const int lr = lane & 15;
  const int kq = lane >> 4;

  const int srow = lane >> 3;
  const int slot = lane & 7;
  const int sgo = (slot ^ srow) * 8;
  const int rloc = w * 8 + srow;

  size_t Aoff[2], Boff[4];
#pragma unroll
  for (int a = 0; a < 2; ++a)
    Aoff[a] = (size_t)(tile_m + a * 64 + rloc) * OP_K + sgo;
#pragma unroll
  for (int b = 0; b < 4; ++b) {
    const int ldsr = b * 64 + rloc;
    const int qn = ldsr >= 128 ? 1 : 0;
    const int rem = ldsr - qn * 128;
    const int wng = rem >> 5;
    const int rr = rem & 31;
    const int gcol = wng * 64 + qn * 32 + rr;
    Boff[b] = (size_t)(tile_n + gcol) * OP_K + sgo;
  }

  f32x4 acc[4][4];
#pragma unroll
  for (int i = 0; i < 4; i++)
#pragma unroll
    for (int j = 0; j < 4; j++) acc[i][j] = (f32x4){0.f, 0.f, 0.f, 0.f};

  auto stageAA = [&](int buf, int k0) {
#pragma unroll
    for (int a = 0; a < 2; ++a)
      gload_lds16(A + Aoff[a] + k0, &smem[buf][(a * 64 + w * 8) * 64]);
  };
  auto stageB2 = [&](int buf, int k0, int b0) {
#pragma unroll
    for (int u = 0; u < 2; ++u)
      gload_lds16(Bm + Boff[b0 + u] + k0,
                  &smem[buf][8192 + ((b0 + u) * 64 + w * 8) * 64]);
  };

  // prologue: A(0), B(0), A(1); drain A(0)+B01(0) (keep B23(0), A(1))
  stageAA(0, 0);
  stageB2(0, 0, 0);
  stageB2(0, 0, 2);
  stageAA(1, 64);
  VMCNT(4);
  BAR();

  for (int t = 0; t < OP_NT; ++t) {
    const int buf = t & 1;
    const int k0n = (t + 1) * 64;
    const bool h1 = (t + 1 < OP_NT);
    const bool h2 = (t + 2 < OP_NT);
    const bf16* ldsA = smem[buf];
    const bf16* ldsB = smem[buf] + 8192;

    bf16x8 af[2][2], b0f[2][2], b1f[2][2];

    // ---- p0: read A-q0 + B-q0; stage B0,B1(t+1); MFMA (0,0) ----
#pragma unroll
    for (int mi = 0; mi < 2; ++mi)
#pragma unroll
      for (int ks = 0; ks < 2; ++ks)
        af[mi][ks] = *(const bf16x8*)&ldsA[(wm * 64 + mi * 16 + lr) * 64 +
                                           (((ks * 4 + kq) ^ (lr & 7)) * 8)];
#pragma unroll
    for (int ni = 0; ni < 2; ++ni)
#pragma unroll
      for (int ks = 0; ks < 2; ++ks)
        b0f[ni][ks] = *(const bf16x8*)&ldsB[(wn * 32 + ni * 16 + lr) * 64 +
                                            (((ks * 4 + kq) ^ (lr & 7)) * 8)];
    if (h1) stageB2(buf ^ 1, k0n, 0);
    BAR();
    __builtin_amdgcn_s_setprio(1);
#pragma unroll
    for (int mi = 0; mi < 2; ++mi)
#pragma unroll
      for (int ni = 0; ni < 2; ++ni)
#pragma unroll
        for (int ks = 0; ks < 2; ++ks)
          acc[mi][ni] = __builtin_amdgcn_mfma_f32_16x16x32_bf16(
              af[mi][ks], b0f[ni][ks], acc[mi][ni], 0, 0, 0);
    __builtin_amdgcn_s_setprio(0);
    if (h1) VMCNT(4);
    else VMCNT(0);
    BAR();

    // ---- p1: read B-q1; stage B2,B3(t+1); MFMA (0,1) ----
#pragma unroll
    for (int ni = 0; ni < 2; ++ni)
#pragma unroll
      for (int ks = 0; ks < 2; ++ks)
        b1f[ni][ks] = *(const bf16x8*)&ldsB[(128 + wn * 32 + ni * 16 + lr) * 64 +
                                            (((ks * 4 + kq) ^ (lr & 7)) * 8)];
    if (h1) stageB2(buf ^ 1, k0n, 2);
    BAR();
    __builtin_amdgcn_s_setprio(1);
#pragma unroll
    for (int mi = 0; mi < 2; ++mi)
#pragma unroll
      for (int ni = 0; ni < 2; ++ni)
#pragma unroll
        for (int ks = 0; ks < 2; ++ks)
          acc[mi][2 + ni] = __builtin_amdgcn_mfma_f32_16x16x32_bf16(
              af[mi][ks], b1f[ni][ks], acc[mi][2 + ni], 0, 0, 0);
    __builtin_amdgcn_s_setprio(0);
    BAR();

    // ---- p2: read A-q1 (overwrite); MFMA (1,1) ----
#pragma unroll
    for (int mi = 0; mi < 2; ++mi)
#pragma unroll
      for (int ks = 0; ks < 2; ++ks)
        af[mi][ks] = *(const bf16x8*)&ldsA[(wm * 64 + 32 + mi * 16 + lr) * 64 +
                                           (((ks * 4 + kq) ^ (lr & 7)) * 8)];
    BAR();
    __builtin_amdgcn_s_setprio(1);
#pragma unroll
    for (int mi = 0; mi < 2; ++mi)
#pragma unroll
      for (int ni = 0; ni < 2; ++ni)
#pragma unroll
        for (int ks = 0; ks < 2; ++ks)
          acc[2 + mi][2 + ni] = __builtin_amdgcn_mfma_f32_16x16x32_bf16(
              af[mi][ks], b1f[ni][ks], acc[2 + mi][2 + ni], 0, 0, 0);
    __builtin_amdgcn_s_setprio(0);
    BAR();

    // ---- p3: no reads (B-q0 live); stage A(t+2) into CURRENT buf; MFMA (1,0)
    if (h2) stageAA(buf, (t + 2) * 64);
    BAR();
    __builtin_amdgcn_s_setprio(1);
#pragma unroll
    for (int mi = 0; mi < 2; ++mi)
#pragma unroll
      for (int ni = 0; ni < 2; ++ni)
#pragma unroll
        for (int ks = 0; ks < 2; ++ks)
          acc[2 + mi][ni] = __builtin_amdgcn_mfma_f32_16x16x32_bf16(
              af[mi][ks], b0f[ni][ks], acc[2 + mi][ni], 0, 0, 0);
    __builtin_amdgcn_s_setprio(0);
    if (h1) {
      if (h2) VMCNT(4);
      else VMCNT(2);
    }
    BAR();
  }

  // epilogue: fp32 C, 64B-coalesced per 16-lane group
  const int rb = kq * 4;
#pragma unroll
  for (int i = 0; i < 4; ++i) {
    const int row0 = tile_m + wm * 64 + (i >> 1) * 32 + (i & 1) * 16 + rb;
#pragma unroll
    for (int j = 0; j < 4; ++j) {
      const int col = tile_n + wn * 64 + (j >> 1) * 32 + (j & 1) * 16 + lr;
#pragma unroll
      for (int r2 = 0; r2 < 4; ++r2)
        C[(size_t)(row0 + r2) * 2048 + col] = acc[i][j][r2];
    }
  }
}

// ---------------------------------------------------------------------------
// RoPE in place on bf16 q and k, cos/sin from precomputed table.
// ---------------------------------------------------------------------------
__global__ __launch_bounds__(256) void rope_kernel(bf16* __restrict__ q,
                                                   bf16* __restrict__ k,
                                                   const float2* __restrict__ cs) {
  int idx = blockIdx.x * 256 + threadIdx.x;  // < 524288
  int j0 = (idx & 15) * 4;
  int nh = idx >> 4;  // n*8 + h, n < 4096
  int s = (nh >> 3) & (S_LEN - 1);
  size_t base = (size_t)nh * 128 + j0;
  bf16x4 qa = *(bf16x4*)&q[base], qb = *(bf16x4*)&q[base + 64];
  bf16x4 ka = *(bf16x4*)&k[base], kb = *(bf16x4*)&k[base + 64];
  const float2* c4 = cs + s * 64 + j0;
#pragma unroll
  for (int jj = 0; jj < 4; jj++) {
    float c = c4[jj].x;
    float sn = c4[jj].y;
    float q1 = (float)qa[jj], q2 = (float)qb[jj];
    qa[jj] = (bf16)(q1 * c - q2 * sn);
    qb[jj] = (bf16)(q2 * c + q1 * sn);
    float k1 = (float)ka[jj], k2 = (float)kb[jj];
    ka[jj] = (bf16)(k1 * c - k2 * sn);
    kb[jj] = (bf16)(k2 * c + k1 * sn);
  }
  *(bf16x4*)&q[base] = qa;
  *(bf16x4*)&q[base + 64] = qb;
  *(bf16x4*)&k[base] = ka;
  *(bf16x4*)&k[base + 64] = kb;
}

// ---------------------------------------------------------------------------
// MFMA banded-decay attention. One block per (s-block 64, h, b); 4 waves,
// each wave owns 16 q rows. QK^T and PV via 16x16x32 bf16 MFMA.
// ---------------------------------------------------------------------------
__global__ __launch_bounds__(256) void attn_mfma_kernel(
    const bf16* __restrict__ q, const bf16* __restrict__ k,
    const bf16* __restrict__ vt, const float* __restrict__ beta,
    const float* __restrict__ la_mean, bf16* __restrict__ outb) {
  const int s0 = blockIdx.x * 64;
  const int h = blockIdx.y;
  const int b = blockIdx.z;
  const int tid = threadIdx.x;
  const int w = tid >> 6;
  const int lane = tid & 63;
  const int lr = lane & 15;
  const int kq = lane >> 4;  // quad
  const float la = la_mean[h];

  __shared__ __align__(16) bf16 Ps[4][2][16][72];

  const int sg = s0 + w * 16;
  const size_t qbase =
      ((size_t)b * S_LEN + (sg + lr)) * INNER_DIM + h * 128 + kq * 8;
  bf16x8 aq[4];
#pragma unroll
  for (int ks = 0; ks < 4; ks++)
    aq[ks] = *(const bf16x8*)&q[qbase + ks * 32];

  f32x4 O[8];
#pragma unroll
  for (int en = 0; en < 8; en++) O[en] = (f32x4){0.f, 0.f, 0.f, 0.f};

  const size_t kbase = (size_t)b * S_LEN * INNER_DIM + h * 128 + kq * 8;
  const size_t vtbase = ((size_t)b * 8 + h) * 128 * 2048;

#pragma unroll
  for (int tile = 0; tile < 2; tile++) {
    const int tb = s0 - 64 + tile * 64;
    f32x4 sc[4];
#pragma unroll
    for (int nt = 0; nt < 4; nt++) sc[nt] = (f32x4){0.f, 0.f, 0.f, 0.f};
#pragma unroll
    for (int nt = 0; nt < 4; nt++) {
      int t = tb + nt * 16 + lr;
      int tc = t > 0 ? t : 0;
#pragma unroll
      for (int ks = 0; ks < 4; ks++) {
        bf16x8 bk = *(const bf16x8*)&k[kbase + (size_t)tc * INNER_DIM + ks * 32];
        sc[nt] = __builtin_amdgcn_mfma_f32_16x16x32_bf16(aq[ks], bk, sc[nt],
                                                         0, 0, 0);
      }
    }
#pragma unroll
    for (int nt = 0; nt < 4; nt++) {
      int t = tb + nt * 16 + lr;
      int tc = t > 0 ? t : 0;
      float bt = beta[((size_t)b * S_LEN + tc) * 8 + h];
#pragma unroll
      for (int reg = 0; reg < 4; reg++) {
        int qrow = sg + kq * 4 + reg;
        int td = qrow - t;
        float wgt = 0.0f;
        if (t >= 0 && td >= 0 && td < 64)
          wgt = sc[nt][reg] * __expf((float)td * la) * bt;
        Ps[w][tile][kq * 4 + reg][nt * 16 + lr] = (bf16)wgt;
      }
    }
    __syncthreads();
    bf16x8 ap[2];
#pragma unroll
    for (int ks2 = 0; ks2 < 2; ks2++)
      ap[ks2] = *(const bf16x8*)&Ps[w][tile][lr][ks2 * 32 + kq * 8];
#pragma unroll
    for (int en = 0; en < 8; en++) {
#pragma unroll
      for (int ks2 = 0; ks2 < 2; ks2++) {
        int t0f = tb + ks2 * 32 + kq * 8;
        int tcf = t0f > 0 ? t0f : 0;
        bf16x8 bv = *(const bf16x8*)&vt[vtbase + (size_t)(en * 16 + lr) * 2048 +
                                        tcf];
        O[en] = __builtin_amdgcn_mfma_f32_16x16x32_bf16(ap[ks2], bv, O[en], 0,
                                                        0, 0);
      }
    }
  }
  const size_t obase = (size_t)b * S_LEN * INNER_DIM + h * 128;
#pragma unroll
  for (int en = 0; en < 8; en++) {
#pragma unroll
    for (int reg = 0; reg < 4; reg++) {
      int qrow = sg + kq * 4 + reg;
      outb[obase + (size_t)qrow * INNER_DIM + en * 16 + lr] =
          (bf16)O[en][reg];
    }
  }
}

// ---------------------------------------------------------------------------
// Stage 1: partial state per 32-step chunk (bf16 k/v inputs), no atomics.
// ---------------------------------------------------------------------------
__global__ __launch_bounds__(256) void state_partial_kernel(
    const bf16* __restrict__ k, const bf16* __restrict__ v,
    const float* __restrict__ beta, const float* __restrict__ la_d,
    float* __restrict__ part) {
  const int bh = blockIdx.x;
  const int chunk = blockIdx.y;
  const int b = bh >> 3, h = bh & 7;
  const int t0 = S_LEN - 512 + chunk * 32;
  const int tid = threadIdx.x;
  const int d = tid >> 1;
  const int eh = (tid & 1) * 64;

  __shared__ float ks[32][128];
  __shared__ float vsm[32][128];
  __shared__ float bs[32];

  const size_t bh_off = ((size_t)b * S_LEN) * INNER_DIM + (size_t)h * 128;
  for (int u = tid; u < 32 * 16; u += 256) {
    int r = u >> 4, c8 = (u & 15) * 8;
    bf16x8 kv = *(const bf16x8*)&k[bh_off + (size_t)(t0 + r) * INNER_DIM + c8];
    bf16x8 vv = *(const bf16x8*)&v[bh_off + (size_t)(t0 + r) * INNER_DIM + c8];
#pragma unroll
    for (int j = 0; j < 8; j++) {
      ks[r][c8 + j] = (float)kv[j];
      vsm[r][c8 + j] = (float)vv[j];
    }
  }
  if (tid < 32) bs[tid] = beta[((size_t)b * S_LEN + t0 + tid) * 8 + h];
  __syncthreads();

  const float lad = la_d[h * 128 + d];
  float acc[64];
#pragma unroll
  for (int e = 0; e < 64; e++) acc[e] = 0.0f;

  for (int tl = 0; tl < 32; tl++) {
    int m = (S_LEN - 1) - (t0 + tl);
    float f = __expf((float)m * lad);
    float coef = bs[tl] * ks[tl][d] * f;
    if (coef != 0.0f) {
#pragma unroll
      for (int e = 0; e < 64; e += 4) {
        float4 vv = *(const float4*)&vsm[tl][eh + e];
        acc[e + 0] = fmaf(coef, vv.x, acc[e + 0]);
        acc[e + 1] = fmaf(coef, vv.y, acc[e + 1]);
        acc[e + 2] = fmaf(coef, vv.z, acc[e + 2]);
        acc[e + 3] = fmaf(coef, vv.w, acc[e + 3]);
      }
    }
  }
  float* pp = part + (((size_t)chunk * 16 + bh) * 16384 + (size_t)d * 128 + eh);
#pragma unroll
  for (int e = 0; e < 64; e += 4) {
    float4 o = {acc[e + 0], acc[e + 1], acc[e + 2], acc[e + 3]};
    *(float4*)&pp[e] = o;
  }
}

// ---------------------------------------------------------------------------
// Stage 2: sum the 16 chunk partials into the final state.
// ---------------------------------------------------------------------------
__global__ __launch_bounds__(256) void state_reduce_kernel(
    const float* __restrict__ part, float* __restrict__ state) {
  size_t off = ((size_t)blockIdx.x * 256 + threadIdx.x) * 4;
  float4 s = {0.f, 0.f, 0.f, 0.f};
#pragma unroll
  for (int c = 0; c < 16; c++) {
    float4 p = *(const float4*)&part[(size_t)c * 262144 + off];
    s.x += p.x; s.y += p.y; s.z += p.z; s.w += p.w;
  }
  *(float4*)&state[off] = s;
}

// ---------------------------------------------------------------------------
extern "C" void kernel_launch(void* const* d_in, const int* in_sizes, int n_in,
                              void* d_out, int out_size, void* d_ws,
                              size_t ws_size, hipStream_t stream) {
  const float* x = (const float*)d_in[0];
  const float* Wq = (const float*)d_in[1];
  const float* Wk = (const float*)d_in[2];
  const float* Wv = (const float*)d_in[3];
  const float* Wo = (const float*)d_in[4];
  const float* Wb = (const float*)d_in[5];
  const float* bb = (const float*)d_in[6];
  const float* alog = (const float*)d_in[7];
  float* out = (float*)d_out;

  char* ws = (char*)d_ws;
  bf16* xb = (bf16*)(ws);                      // 16 MB
  float* part = (float*)(ws);                  // reuses xb after QKV GEMM
  bf16* wqkvb = (bf16*)(ws + 16777216UL);      // 12 MB
  bf16* wob = (bf16*)(ws + 29360128UL);        // 4 MB
  bf16* q = (bf16*)(ws + 33554432UL);          // 8 MB
  bf16* kk = (bf16*)(ws + 41943040UL);         // 8 MB
  bf16* vv = (bf16*)(ws + 50331648UL);         // 8 MB
  bf16* attnb = (bf16*)(ws + 58720256UL);      // 8 MB
  bf16* vt = (bf16*)(ws + 67108864UL);         // 8 MB (V transposed)
  float* beta = (float*)(ws + 75497472UL);     // 128 KB
  float* la_mean = (float*)(ws + 75628544UL);  // 32 B
  float* la_d = (float*)(ws + 75628800UL);     // 4 KB
  float2* cs = (float2*)(ws + 75632896UL);     // 1 MB rope table

  // fused prep: weight convert + beta/xb + rope table + alpha
  prep_kernel<<<9736, 256, 0, stream>>>(x, Wq, Wk, Wv, Wo, Wb, bb, alog,
                                        wqkvb, wob, xb, beta, la_mean, la_d,
                                        cs);
  // fused QKV GEMM (128x384 4-phase, full-fill 256 blocks) -> q/kk/vv (+ vt)
  qkv_gemm8p_kernel<<<256, 512, 0, stream>>>(xb, wqkvb, q, vt);
  rope_kernel<<<2048, 256, 0, stream>>>(q, kk, cs);
  attn_mfma_kernel<<<dim3(S_LEN / 64, NHEADS, BATCH), 256, 0, stream>>>(
      q, kk, vt, beta, la_mean, attnb);
  state_partial_kernel<<<dim3(16, 16), 256, 0, stream>>>(kk, vv, beta, la_d,
                                                         part);
  state_reduce_kernel<<<256, 256, 0, stream>>>(part, out + 8388608);
  // output projection (128x256 4-phase, full-fill 256 blocks) -> fp32 out
  oproj_kernel<<<256, 512, 0, stream>>>(attnb, wob, out);
}

// Round 6
// 262.447 us; speedup vs baseline: 1.0196x; 1.0196x over previous
//
#include <hip/hip_runtime.h>
#include <hip/hip_bf16.h>
#include <cstdint>
#include <cstddef>

// Problem constants
#define S_LEN 2048
#define DMODEL 2048
#define NHEADS 8
#define DHEAD 128
#define INNER_DIM 1024
#define BATCH 2

typedef __bf16 bf16;
typedef __bf16 bf16x8 __attribute__((ext_vector_type(8)));
typedef __bf16 bf16x4 __attribute__((ext_vector_type(4)));
typedef float f32x4 __attribute__((ext_vector_type(4)));

#define VMCNT(n) asm volatile("s_waitcnt vmcnt(" #n ")" ::: "memory")
#define BAR()                                \
  do {                                       \
    asm volatile("" ::: "memory");           \
    __builtin_amdgcn_s_barrier();            \
    asm volatile("" ::: "memory");           \
  } while (0)

__device__ __forceinline__ void gload_lds16(const void* g, void* l) {
  __builtin_amdgcn_global_load_lds(
      (const __attribute__((address_space(1))) void*)g,
      (__attribute__((address_space(3))) void*)l, 16, 0, 0);
}

__device__ __forceinline__ float sigmoidf_(float x) {
  return 1.0f / (1.0f + expf(-x));
}

// ---------------------------------------------------------------------------
// Fused prep kernel, range-dispatched on blockIdx.x (unchanged from round 5).
// ---------------------------------------------------------------------------
__global__ __launch_bounds__(256) void prep_kernel(
    const float* __restrict__ x, const float* __restrict__ wq,
    const float* __restrict__ wk, const float* __restrict__ wv,
    const float* __restrict__ wo, const float* __restrict__ Wb,
    const float* __restrict__ bbias, const float* __restrict__ alpha_log,
    bf16* __restrict__ wqkvb, bf16* __restrict__ wob, bf16* __restrict__ xb,
    float* __restrict__ beta, float* __restrict__ la_mean,
    float* __restrict__ la_d, float2* __restrict__ cs) {
  const int bid = blockIdx.x;
  const int tid = threadIdx.x;

  if (bid < 8192) {
    size_t i4 = ((size_t)bid * 256 + tid) * 4;
    const float* src;
    bf16* dst;
    size_t off;
    if (i4 < 2097152UL)       { src = wq; dst = wqkvb;           off = i4; }
    else if (i4 < 4194304UL)  { src = wk; dst = wqkvb + 2097152; off = i4 - 2097152UL; }
    else if (i4 < 6291456UL)  { src = wv; dst = wqkvb + 4194304; off = i4 - 4194304UL; }
    else                      { src = wo; dst = wob;             off = i4 - 6291456UL; }
    float4 v = *(const float4*)(src + off);
    bf16x4 o;
    o[0] = (bf16)v.x; o[1] = (bf16)v.y; o[2] = (bf16)v.z; o[3] = (bf16)v.w;
    *(bf16x4*)(dst + off) = o;
  } else if (bid < 9216) {
    const int n = (bid - 8192) * 4 + (tid >> 6);
    const int lane = tid & 63;
    float acc[8];
#pragma unroll
    for (int h = 0; h < 8; h++) acc[h] = 0.0f;
    const float4* x4 = (const float4*)(x + (size_t)n * DMODEL);
    bf16* xbr = xb + (size_t)n * DMODEL;
    for (int d4 = lane; d4 < DMODEL / 4; d4 += 64) {
      float4 xv = x4[d4];
      bf16x4 o;
      o[0] = (bf16)xv.x; o[1] = (bf16)xv.y; o[2] = (bf16)xv.z; o[3] = (bf16)xv.w;
      *(bf16x4*)(xbr + d4 * 4) = o;
#pragma unroll
      for (int h = 0; h < 8; h++) {
        float4 wv2 = ((const float4*)(Wb + (size_t)h * DMODEL))[d4];
        acc[h] += xv.x * wv2.x + xv.y * wv2.y + xv.z * wv2.z + xv.w * wv2.w;
      }
    }
#pragma unroll
    for (int off = 32; off; off >>= 1)
#pragma unroll
      for (int h = 0; h < 8; h++) acc[h] += __shfl_down(acc[h], off);
    if (lane == 0) {
#pragma unroll
      for (int h = 0; h < 8; h++)
        beta[(size_t)n * 8 + h] = sigmoidf_(acc[h] + bbias[h]);
    }
  } else if (bid < 9728) {
    int idx = (bid - 9216) * 256 + tid;  // < 131072 = 2048*64
    int s = idx >> 6, j = idx & 63;
    float f = (float)s * expf(-(float)j * (9.210340371976184f / 64.0f));
    float sn, c;
    sincosf(f, &sn, &c);
    cs[idx] = make_float2(c, sn);
  } else {
    if (tid >= 64) return;
    const int h = bid - 9728;
    const int lane = tid;
    float a1 = sigmoidf_(alpha_log[h * 128 + lane]);
    float a2 = sigmoidf_(alpha_log[h * 128 + 64 + lane]);
    la_d[h * 128 + lane] = logf(a1);
    la_d[h * 128 + 64 + lane] = logf(a2);
    float s = a1 + a2;
    for (int off = 32; off; off >>= 1) s += __shfl_down(s, off);
    if (lane == 0) la_mean[h] = logf(fmaxf(s * (1.0f / 128.0f), 1e-6f));
  }
}

// ---------------------------------------------------------------------------
// QKV projection: 128x384-tile 4-phase bf16 GEMM, full-fill 256 blocks.
// ROUND-6 RESTRUCTURE: ONE barrier per phase (was 2) — 4 barriers/K-tile.
// Phase = {ds_reads; stage-issue; MFMA (lgkm auto); [counted vmcnt]; BAR}.
// Hazard proof:
//  - intra-phase read->MFMA: per-wave lgkmcnt (compiler).
//  - DMA(write buf^1 region R) vs prior reads of R: R last read tile t-1;
//    those reads lgkm-complete before each wave's MFMA, hence before t-1's
//    final BAR; stage issued after that BAR. Safe.
//  - reads of freshly staged R: every wave drains own DMAs to the counted
//    watermark, then BAR publishes -> reads next phase. Safe.
//  - p3's A(t+2) into CURRENT buf: A-q1 reads (p2) lgkm-complete before
//    p2-end BAR; stage issued after it. Safe.
// vmcnt ledger (2 loads per stage op; issue order/tile: b01,b23,b45(t+1),
// aa(t+2)); invariant entering p0(t): outstanding = [b45(t), aa(t+1)]:
//  p0-end: VMCNT(4) (drains b45(t); last tile: VMCNT(0))
//  p3-end: VMCNT(4) (drains b01,b23(t+1)+aa(t+1); t=NT-2: VMCNT(2))
// Prologue: aa(0),b01(0),b23(0),aa(1),b45(0); VMCNT(4); BAR.
// ---------------------------------------------------------------------------
#define QKV_K 2048
#define QKV_NT 32  // K / 64

__global__ __launch_bounds__(512, 2) void qkv_gemm8p_kernel(
    const bf16* __restrict__ A, const bf16* __restrict__ Bm,
    bf16* __restrict__ C, bf16* __restrict__ vt) {
  __shared__ __align__(16) bf16 smem[2][32768];  // buf: A[0,8192) B[8192,32768)

  const int id = blockIdx.x;
  const int wg = (id & 7) * 32 + (id >> 3);
  const int tile_n = (wg >> 5) * 384;
  const int tile_m = (wg & 31) * 128;

  const int tid = threadIdx.x;
  const int lane = tid & 63;
  const int w = tid >> 6;
  const int wm = w >> 2;  // 0..1 -> rows wm*64
  const int wn = w & 3;   // 0..3 -> cols wn*96
  const int lr = lane & 15;
  const int kq = lane >> 4;

  const int srow = lane >> 3;
  const int slot = lane & 7;
  const int sgo = (slot ^ srow) * 8;
  const int rloc = w * 8 + srow;

  size_t Aoff[2], Boff[6];
#pragma unroll
  for (int a = 0; a < 2; ++a)
    Aoff[a] = (size_t)(tile_m + a * 64 + rloc) * QKV_K + sgo;
#pragma unroll
  for (int b = 0; b < 6; ++b) {
    const int ldsr = b * 64 + rloc;
    const int qn = ldsr >= 192 ? 1 : 0;
    const int rem = ldsr - qn * 192;
    const int wng = rem / 48;
    const int rr = rem - wng * 48;
    const int gcol = wng * 96 + qn * 48 + rr;
    Boff[b] = (size_t)(tile_n + gcol) * QKV_K + sgo;
  }

  f32x4 acc[4][6];
#pragma unroll
  for (int i = 0; i < 4; i++)
#pragma unroll
    for (int j = 0; j < 6; j++) acc[i][j] = (f32x4){0.f, 0.f, 0.f, 0.f};

  auto stageAA = [&](int buf, int k0) {
#pragma unroll
    for (int a = 0; a < 2; ++a)
      gload_lds16(A + Aoff[a] + k0, &smem[buf][(a * 64 + w * 8) * 64]);
  };
  auto stageB2 = [&](int buf, int k0, int b0) {
#pragma unroll
    for (int u = 0; u < 2; ++u)
      gload_lds16(Bm + Boff[b0 + u] + k0,
                  &smem[buf][8192 + ((b0 + u) * 64 + w * 8) * 64]);
  };

  // prologue (order matters for the ledger)
  stageAA(0, 0);
  stageB2(0, 0, 0);
  stageB2(0, 0, 2);
  stageAA(1, 64);
  stageB2(0, 0, 4);
  VMCNT(4);
  BAR();

  for (int t = 0; t < QKV_NT; ++t) {
    const int buf = t & 1;
    const int k0n = (t + 1) * 64;
    const bool h1 = (t + 1 < QKV_NT);
    const bool h2 = (t + 2 < QKV_NT);
    const bf16* ldsA = smem[buf];
    const bf16* ldsB = smem[buf] + 8192;

    bf16x8 af[2][2], b0f[3][2], b1f[3][2];

    // ---- p0: read A-q0 + B-q0; stage b01(t+1); MFMA (0,0..2) ----
#pragma unroll
    for (int mi = 0; mi < 2; ++mi)
#pragma unroll
      for (int ks = 0; ks < 2; ++ks)
        af[mi][ks] = *(const bf16x8*)&ldsA[(wm * 64 + mi * 16 + lr) * 64 +
                                           (((ks * 4 + kq) ^ (lr & 7)) * 8)];
#pragma unroll
    for (int ni = 0; ni < 3; ++ni)
#pragma unroll
      for (int ks = 0; ks < 2; ++ks)
        b0f[ni][ks] = *(const bf16x8*)&ldsB[(wn * 48 + ni * 16 + lr) * 64 +
                                            (((ks * 4 + kq) ^ (lr & 7)) * 8)];
    if (h1) stageB2(buf ^ 1, k0n, 0);
    __builtin_amdgcn_s_setprio(1);
#pragma unroll
    for (int mi = 0; mi < 2; ++mi)
#pragma unroll
      for (int ni = 0; ni < 3; ++ni)
#pragma unroll
        for (int ks = 0; ks < 2; ++ks)
          acc[mi][ni] = __builtin_amdgcn_mfma_f32_16x16x32_bf16(
              af[mi][ks], b0f[ni][ks], acc[mi][ni], 0, 0, 0);
    __builtin_amdgcn_s_setprio(0);
    if (h1) VMCNT(4);
    else VMCNT(0);
    BAR();

    // ---- p1: read B-q1; stage b23(t+1); MFMA (0,3..5) ----
#pragma unroll
    for (int ni = 0; ni < 3; ++ni)
#pragma unroll
      for (int ks = 0; ks < 2; ++ks)
        b1f[ni][ks] = *(const bf16x8*)&ldsB[(192 + wn * 48 + ni * 16 + lr) * 64 +
                                            (((ks * 4 + kq) ^ (lr & 7)) * 8)];
    if (h1) stageB2(buf ^ 1, k0n, 2);
    __builtin_amdgcn_s_setprio(1);
#pragma unroll
    for (int mi = 0; mi < 2; ++mi)
#pragma unroll
      for (int ni = 0; ni < 3; ++ni)
#pragma unroll
        for (int ks = 0; ks < 2; ++ks)
          acc[mi][3 + ni] = __builtin_amdgcn_mfma_f32_16x16x32_bf16(
              af[mi][ks], b1f[ni][ks], acc[mi][3 + ni], 0, 0, 0);
    __builtin_amdgcn_s_setprio(0);
    BAR();

    // ---- p2: read A-q1 (overwrite); stage b45(t+1); MFMA (1,3..5) ----
#pragma unroll
    for (int mi = 0; mi < 2; ++mi)
#pragma unroll
      for (int ks = 0; ks < 2; ++ks)
        af[mi][ks] = *(const bf16x8*)&ldsA[(wm * 64 + 32 + mi * 16 + lr) * 64 +
                                           (((ks * 4 + kq) ^ (lr & 7)) * 8)];
    if (h1) stageB2(buf ^ 1, k0n, 4);
    __builtin_amdgcn_s_setprio(1);
#pragma unroll
    for (int mi = 0; mi < 2; ++mi)
#pragma unroll
      for (int ni = 0; ni < 3; ++ni)
#pragma unroll
        for (int ks = 0; ks < 2; ++ks)
          acc[2 + mi][3 + ni] = __builtin_amdgcn_mfma_f32_16x16x32_bf16(
              af[mi][ks], b1f[ni][ks], acc[2 + mi][3 + ni], 0, 0, 0);
    __builtin_amdgcn_s_setprio(0);
    BAR();

    // ---- p3: stage A(t+2) into CURRENT buf; MFMA (1,0..2) ----
    if (h2) stageAA(buf, (t + 2) * 64);
    __builtin_amdgcn_s_setprio(1);
#pragma unroll
    for (int mi = 0; mi < 2; ++mi)
#pragma unroll
      for (int ni = 0; ni < 3; ++ni)
#pragma unroll
        for (int ks = 0; ks < 2; ++ks)
          acc[2 + mi][ni] = __builtin_amdgcn_mfma_f32_16x16x32_bf16(
              af[mi][ks], b0f[ni][ks], acc[2 + mi][ni], 0, 0, 0);
    __builtin_amdgcn_s_setprio(0);
    if (h1) {
      if (h2) VMCNT(4);
      else VMCNT(2);
    }
    BAR();
  }

  const int rb = kq * 4;
#pragma unroll
  for (int mi = 0; mi < 4; ++mi) {
    const int row0 = tile_m + wm * 64 + mi * 16 + rb;
#pragma unroll
    for (int ni = 0; ni < 6; ++ni) {
      const int col = tile_n + wn * 96 + ni * 16 + lr;
      const int z = col >> 10;
      const int cz = col & 1023;
      bf16* Cz = C + (size_t)z * 4194304UL;
#pragma unroll
      for (int r2 = 0; r2 < 4; ++r2)
        Cz[(size_t)(row0 + r2) * 1024 + cz] = (bf16)acc[mi][ni][r2];
      if (z == 2) {
        const int bb2 = row0 >> 11;
        const int ss = row0 & 2047;
        bf16x4 o4;
#pragma unroll
        for (int r2 = 0; r2 < 4; ++r2) o4[r2] = (bf16)acc[mi][ni][r2];
        *(bf16x4*)&vt[(((size_t)bb2 * 8 + (cz >> 7)) * 128 + (cz & 127)) * 2048 +
                      ss] = o4;
      }
    }
  }
}

// ---------------------------------------------------------------------------
// Output projection: 128x256-tile 4-phase bf16 GEMM -> fp32 C, full-fill
// 256 blocks. ROUND-6: same single-barrier-per-phase restructure.
// Ledger (stage ops/tile: b01(t+1)@p0, b23(t+1)@p1, aa(t+2)@p3; invariant
// entering p0(t): [b23(t), aa(t+1)]):
//  p0-end: VMCNT(4) (last: VMCNT(0)); p3-end: VMCNT(4) (NT-2: VMCNT(2)).
// Prologue: aa(0),b01(0),aa(1),b23(0); VMCNT(4); BAR.
// ---------------------------------------------------------------------------
#define OP_K 1024
#define OP_NT 16  // K / 64

__global__ __launch_bounds__(512, 2) void oproj_kernel(
    const bf16* __restrict__ A, const bf16* __restrict__ Bm,
    float* __restrict__ C) {
  __shared__ __align__(16) bf16 smem[2][24576];  // A[0,8192) B[8192,24576)

  const int id = blockIdx.x;
  const int wg = (id & 7) * 32 + (id >> 3);
  const int tile_n = (wg >> 5) * 256;
  const int tile_m = (wg & 31) * 128;

  const int tid = threadIdx.x;
  const int lane = tid & 63;
  const int w = tid >> 6;
  const int wm = w >> 2;  // 0..1
  const int wn = w & 3;   // 0..3
  const int lr = lane & 15;
  const int kq = lane >> 4;

  const int srow = lane >> 3;
  const int slot = lane & 7;
  const int sgo = (slot ^ srow) * 8;
  const int rloc = w * 8 + srow;

  size_t Aoff[2], Boff[4];
#pragma unroll
  for (int a = 0; a < 2; ++a)
    Aoff[a] = (size_t)(tile_m + a * 64 + rloc) * OP_K + sgo;
#pragma unroll
  for (int b = 0; b < 4; ++b) {
    const int ldsr = b * 64 + rloc;
    const int qn = ldsr >= 128 ? 1 : 0;
    const int rem = ldsr - qn * 128;
    const int wng = rem >> 5;
    const int rr = rem & 31;
    const int gcol = wng * 64 + qn * 32 + rr;
    Boff[b] = (size_t)(tile_n + gcol) * OP_K + sgo;
  }

  f32x4 acc[4][4];
#pragma unroll
  for (int i = 0; i < 4; i++)
#pragma unroll
    for (int j = 0; j < 4; j++) acc[i][j] = (f32x4){0.f, 0.f, 0.f, 0.f};

  auto stageAA = [&](int buf, int k0) {
#pragma unroll
    for (int a = 0; a < 2; ++a)
      gload_lds16(A + Aoff[a] + k0, &smem[buf][(a * 64 + w * 8) * 64]);
  };
  auto stageB2 = [&](int buf, int k0, int b0) {
#pragma unroll
    for (int u = 0; u < 2; ++u)
      gload_lds16(Bm + Boff[b0 + u] + k0,
                  &smem[buf][8192 + ((b0 + u) * 64 + w * 8) * 64]);
  };

  // prologue
  stageAA(0, 0);
  stageB2(0, 0, 0);
  stageAA(1, 64);
  stageB2(0, 0, 2);
  VMCNT(4);
  BAR();

  for (int t = 0; t < OP_NT; ++t) {
    const int buf = t & 1;
    const int k0n = (t + 1) * 64;
    const bool h1 = (t + 1 < OP_NT);
    const bool h2 = (t + 2 < OP_NT);
    const bf16* ldsA = smem[buf];
    const bf16* ldsB = smem[buf] + 8192;

    bf16x8 af[2][2], b0f[2][2], b1f[2][2];

    // ---- p0: read A-q0 + B-q0; stage b01(t+1); MFMA (0,0..1) ----
#pragma unroll
    for (int mi = 0; mi < 2; ++mi)
#pragma unroll
      for (int ks = 0; ks < 2; ++ks)
        af[mi][ks] = *(const bf16x8*)&ldsA[(wm * 64 + mi * 16 + lr) * 64 +
                                           (((ks * 4 + kq) ^ (lr & 7)) * 8)];
#pragma unroll
    for (int ni = 0; ni < 2; ++ni)
#pragma unroll
      for (int ks = 0; ks < 2; ++ks)
        b0f[ni][ks] = *(const bf16x8*)&ldsB[(wn * 32 + ni * 16 + lr) * 64 +
                                            (((ks * 4 + kq) ^ (lr & 7)) * 8)];
    if (h1) stageB2(buf ^ 1, k0n, 0);
    __builtin_amdgcn_s_setprio(1);
#pragma unroll
    for (int mi = 0; mi < 2; ++mi)
#pragma unroll
      for (int ni = 0; ni < 2; ++ni)
#pragma unroll
        for (int ks = 0; ks < 2; ++ks)
          acc[mi][ni] = __builtin_amdgcn_mfma_f32_16x16x32_bf16(
              af[mi][ks], b0f[ni][ks], acc[mi][ni], 0, 0, 0);
    __builtin_amdgcn_s_setprio(0);
    if (h1) VMCNT(4);
    else VMCNT(0);
    BAR();

    // ---- p1: read B-q1; stage b23(t+1); MFMA (0,2..3) ----
#pragma unroll
    for (int ni = 0; ni < 2; ++ni)
#pragma unroll
      for (int ks = 0; ks < 2; ++ks)
        b1f[ni][ks] = *(const bf16x8*)&ldsB[(128 + wn * 32 + ni * 16 + lr) * 64 +
                                            (((ks * 4 + kq) ^ (lr & 7)) * 8)];
    if (h1) stageB2(buf ^ 1, k0n, 2);
    __builtin_amdgcn_s_setprio(1);
#pragma unroll
    for (int mi = 0; mi < 2; ++mi)
#pragma unroll
      for (int ni = 0; ni < 2; ++ni)
#pragma unroll
        for (int ks = 0; ks < 2; ++ks)
          acc[mi][2 + ni] = __builtin_amdgcn_mfma_f32_16x16x32_bf16(
              af[mi][ks], b1f[ni][ks], acc[mi][2 + ni], 0, 0, 0);
    __builtin_amdgcn_s_setprio(0);
    BAR();

    // ---- p2: read A-q1 (overwrite); MFMA (1,2..3) ----
#pragma unroll
    for (int mi = 0; mi < 2; ++mi)
#pragma unroll
      for (int ks = 0; ks < 2; ++ks)
        af[mi][ks] = *(const bf16x8*)&ldsA[(wm * 64 + 32 + mi * 16 + lr) * 64 +
                                           (((ks * 4 + kq) ^ (lr & 7)) * 8)];
    __builtin_amdgcn_s_setprio(1);
#pragma unroll
    for (int mi = 0; mi < 2; ++mi)
#pragma unroll
      for (int ni = 0; ni < 2; ++ni)
#pragma unroll
        for (int ks = 0; ks < 2; ++ks)
          acc[2 + mi][2 + ni] = __builtin_amdgcn_mfma_f32_16x16x32_bf16(
              af[mi][ks], b1f[ni][ks], acc[2 + mi][2 + ni], 0, 0, 0);
    __builtin_amdgcn_s_setprio(0);
    BAR();

    // ---- p3: stage A(t+2) into CURRENT buf; MFMA (1,0..1) ----
    if (h2) stageAA(buf, (t + 2) * 64);
    __builtin_amdgcn_s_setprio(1);
#pragma unroll
    for (int mi = 0; mi < 2; ++mi)
#pragma unroll
      for (int ni = 0; ni < 2; ++ni)
#pragma unroll
        for (int ks = 0; ks < 2; ++ks)
          acc[2 + mi][ni] = __builtin_amdgcn_mfma_f32_16x16x32_bf16(
              af[mi][ks], b0f[ni][ks], acc[2 + mi][ni], 0, 0, 0);
    __builtin_amdgcn_s_setprio(0);
    if (h1) {
      if (h2) VMCNT(4);
      else VMCNT(2);
    }
    BAR();
  }

  // epilogue: fp32 C, 64B-coalesced per 16-lane group
  const int rb = kq * 4;
#pragma unroll
  for (int i = 0; i < 4; ++i) {
    const int row0 = tile_m + wm * 64 + (i >> 1) * 32 + (i & 1) * 16 + rb;
#pragma unroll
    for (int j = 0; j < 4; ++j) {
      const int col = tile_n + wn * 64 + (j >> 1) * 32 + (j & 1) * 16 + lr;
#pragma unroll
      for (int r2 = 0; r2 < 4; ++r2)
        C[(size_t)(row0 + r2) * 2048 + col] = acc[i][j][r2];
    }
  }
}

// ---------------------------------------------------------------------------
// RoPE in place on bf16 q and k, cos/sin from precomputed table.
// ---------------------------------------------------------------------------
__global__ __launch_bounds__(256) void rope_kernel(bf16* __restrict__ q,
                                                   bf16* __restrict__ k,
                                                   const float2* __restrict__ cs) {
  int idx = blockIdx.x * 256 + threadIdx.x;  // < 524288
  int j0 = (idx & 15) * 4;
  int nh = idx >> 4;  // n*8 + h, n < 4096
  int s = (nh >> 3) & (S_LEN - 1);
  size_t base = (size_t)nh * 128 + j0;
  bf16x4 qa = *(bf16x4*)&q[base], qb = *(bf16x4*)&q[base + 64];
  bf16x4 ka = *(bf16x4*)&k[base], kb = *(bf16x4*)&k[base + 64];
  const float2* c4 = cs + s * 64 + j0;
#pragma unroll
  for (int jj = 0; jj < 4; jj++) {
    float c = c4[jj].x;
    float sn = c4[jj].y;
    float q1 = (float)qa[jj], q2 = (float)qb[jj];
    qa[jj] = (bf16)(q1 * c - q2 * sn);
    qb[jj] = (bf16)(q2 * c + q1 * sn);
    float k1 = (float)ka[jj], k2 = (float)kb[jj];
    ka[jj] = (bf16)(k1 * c - k2 * sn);
    kb[jj] = (bf16)(k2 * c + k1 * sn);
  }
  *(bf16x4*)&q[base] = qa;
  *(bf16x4*)&q[base + 64] = qb;
  *(bf16x4*)&k[base] = ka;
  *(bf16x4*)&k[base + 64] = kb;
}

// ---------------------------------------------------------------------------
// MFMA banded-decay attention (unchanged).
// ---------------------------------------------------------------------------
__global__ __launch_bounds__(256) void attn_mfma_kernel(
    const bf16* __restrict__ q, const bf16* __restrict__ k,
    const bf16* __restrict__ vt, const float* __restrict__ beta,
    const float* __restrict__ la_mean, bf16* __restrict__ outb) {
  const int s0 = blockIdx.x * 64;
  const int h = blockIdx.y;
  const int b = blockIdx.z;
  const int tid = threadIdx.x;
  const int w = tid >> 6;
  const int lane = tid & 63;
  const int lr = lane & 15;
  const int kq = lane >> 4;  // quad
  const float la = la_mean[h];

  __shared__ __align__(16) bf16 Ps[4][2][16][72];

  const int sg = s0 + w * 16;
  const size_t qbase =
      ((size_t)b * S_LEN + (sg + lr)) * INNER_DIM + h * 128 + kq * 8;
  bf16x8 aq[4];
#pragma unroll
  for (int ks = 0; ks < 4; ks++)
    aq[ks] = *(const bf16x8*)&q[qbase + ks * 32];

  f32x4 O[8];
#pragma unroll
  for (int en = 0; en < 8; en++) O[en] = (f32x4){0.f, 0.f, 0.f, 0.f};

  const size_t kbase = (size_t)b * S_LEN * INNER_DIM + h * 128 + kq * 8;
  const size_t vtbase = ((size_t)b * 8 + h) * 128 * 2048;

#pragma unroll
  for (int tile = 0; tile < 2; tile++) {
    const int tb = s0 - 64 + tile * 64;
    f32x4 sc[4];
#pragma unroll
    for (int nt = 0; nt < 4; nt++) sc[nt] = (f32x4){0.f, 0.f, 0.f, 0.f};
#pragma unroll
    for (int nt = 0; nt < 4; nt++) {
      int t = tb + nt * 16 + lr;
      int tc = t > 0 ? t : 0;
#pragma unroll
      for (int ks = 0; ks < 4; ks++) {
        bf16x8 bk = *(const bf16x8*)&k[kbase + (size_t)tc * INNER_DIM + ks * 32];
        sc[nt] = __builtin_amdgcn_mfma_f32_16x16x32_bf16(aq[ks], bk, sc[nt],
                                                         0, 0, 0);
      }
    }
#pragma unroll
    for (int nt = 0; nt < 4; nt++) {
      int t = tb + nt * 16 + lr;
      int tc = t > 0 ? t : 0;
      float bt = beta[((size_t)b * S_LEN + tc) * 8 + h];
#pragma unroll
      for (int reg = 0; reg < 4; reg++) {
        int qrow = sg + kq * 4 + reg;
        int td = qrow - t;
        float wgt = 0.0f;
        if (t >= 0 && td >= 0 && td < 64)
          wgt = sc[nt][reg] * __expf((float)td * la) * bt;
        Ps[w][tile][kq * 4 + reg][nt * 16 + lr] = (bf16)wgt;
      }
    }
    __syncthreads();
    bf16x8 ap[2];
#pragma unroll
    for (int ks2 = 0; ks2 < 2; ks2++)
      ap[ks2] = *(const bf16x8*)&Ps[w][tile][lr][ks2 * 32 + kq * 8];
#pragma unroll
    for (int en = 0; en < 8; en++) {
#pragma unroll
      for (int ks2 = 0; ks2 < 2; ks2++) {
        int t0f = tb + ks2 * 32 + kq * 8;
        int tcf = t0f > 0 ? t0f : 0;
        bf16x8 bv = *(const bf16x8*)&vt[vtbase + (size_t)(en * 16 + lr) * 2048 +
                                        tcf];
        O[en] = __builtin_amdgcn_mfma_f32_16x16x32_bf16(ap[ks2], bv, O[en], 0,
                                                        0, 0);
      }
    }
  }
  const size_t obase = (size_t)b * S_LEN * INNER_DIM + h * 128;
#pragma unroll
  for (int en = 0; en < 8; en++) {
#pragma unroll
    for (int reg = 0; reg < 4; reg++) {
      int qrow = sg + kq * 4 + reg;
      outb[obase + (size_t)qrow * INNER_DIM + en * 16 + lr] =
          (bf16)O[en][reg];
    }
  }
}

// ---------------------------------------------------------------------------
// Stage 1: partial state per 32-step chunk (bf16 k/v inputs), no atomics.
// ---------------------------------------------------------------------------
__global__ __launch_bounds__(256) void state_partial_kernel(
    const bf16* __restrict__ k, const bf16* __restrict__ v,
    const float* __restrict__ beta, const float* __restrict__ la_d,
    float* __restrict__ part) {
  const int bh = blockIdx.x;
  const int chunk = blockIdx.y;
  const int b = bh >> 3, h = bh & 7;
  const int t0 = S_LEN - 512 + chunk * 32;
  const int tid = threadIdx.x;
  const int d = tid >> 1;
  const int eh = (tid & 1) * 64;

  __shared__ float ks[32][128];
  __shared__ float vsm[32][128];
  __shared__ float bs[32];

  const size_t bh_off = ((size_t)b * S_LEN) * INNER_DIM + (size_t)h * 128;
  for (int u = tid; u < 32 * 16; u += 256) {
    int r = u >> 4, c8 = (u & 15) * 8;
    bf16x8 kv = *(const bf16x8*)&k[bh_off + (size_t)(t0 + r) * INNER_DIM + c8];
    bf16x8 vv = *(const bf16x8*)&v[bh_off + (size_t)(t0 + r) * INNER_DIM + c8];
#pragma unroll
    for (int j = 0; j < 8; j++) {
      ks[r][c8 + j] = (float)kv[j];
      vsm[r][c8 + j] = (float)vv[j];
    }
  }
  if (tid < 32) bs[tid] = beta[((size_t)b * S_LEN + t0 + tid) * 8 + h];
  __syncthreads();

  const float lad = la_d[h * 128 + d];
  float acc[64];
#pragma unroll
  for (int e = 0; e < 64; e++) acc[e] = 0.0f;

  for (int tl = 0; tl < 32; tl++) {
    int m = (S_LEN - 1) - (t0 + tl);
    float f = __expf((float)m * lad);
    float coef = bs[tl] * ks[tl][d] * f;
    if (coef != 0.0f) {
#pragma unroll
      for (int e = 0; e < 64; e += 4) {
        float4 vv = *(const float4*)&vsm[tl][eh + e];
        acc[e + 0] = fmaf(coef, vv.x, acc[e + 0]);
        acc[e + 1] = fmaf(coef, vv.y, acc[e + 1]);
        acc[e + 2] = fmaf(coef, vv.z, acc[e + 2]);
        acc[e + 3] = fmaf(coef, vv.w, acc[e + 3]);
      }
    }
  }
  float* pp = part + (((size_t)chunk * 16 + bh) * 16384 + (size_t)d * 128 + eh);
#pragma unroll
  for (int e = 0; e < 64; e += 4) {
    float4 o = {acc[e + 0], acc[e + 1], acc[e + 2], acc[e + 3]};
    *(float4*)&pp[e] = o;
  }
}

// ---------------------------------------------------------------------------
// Stage 2: sum the 16 chunk partials into the final state.
// ---------------------------------------------------------------------------
__global__ __launch_bounds__(256) void state_reduce_kernel(
    const float* __restrict__ part, float* __restrict__ state) {
  size_t off = ((size_t)blockIdx.x * 256 + threadIdx.x) * 4;
  float4 s = {0.f, 0.f, 0.f, 0.f};
#pragma unroll
  for (int c = 0; c < 16; c++) {
    float4 p = *(const float4*)&part[(size_t)c * 262144 + off];
    s.x += p.x; s.y += p.y; s.z += p.z; s.w += p.w;
  }
  *(float4*)&state[off] = s;
}

// ---------------------------------------------------------------------------
extern "C" void kernel_launch(void* const* d_in, const int* in_sizes, int n_in,
                              void* d_out, int out_size, void* d_ws,
                              size_t ws_size, hipStream_t stream) {
  const float* x = (const float*)d_in[0];
  const float* Wq = (const float*)d_in[1];
  const float* Wk = (const float*)d_in[2];
  const float* Wv = (const float*)d_in[3];
  const float* Wo = (const float*)d_in[4];
  const float* Wb = (const float*)d_in[5];
  const float* bb = (const float*)d_in[6];
  const float* alog = (const float*)d_in[7];
  float* out = (float*)d_out;

  char* ws = (char*)d_ws;
  bf16* xb = (bf16*)(ws);                      // 16 MB
  float* part = (float*)(ws);                  // reuses xb after QKV GEMM
  bf16* wqkvb = (bf16*)(ws + 16777216UL);      // 12 MB
  bf16* wob = (bf16*)(ws + 29360128UL);        // 4 MB
  bf16* q = (bf16*)(ws + 33554432UL);          // 8 MB
  bf16* kk = (bf16*)(ws + 41943040UL);         // 8 MB
  bf16* vv = (bf16*)(ws + 50331648UL);         // 8 MB
  bf16* attnb = (bf16*)(ws + 58720256UL);      // 8 MB
  bf16* vt = (bf16*)(ws + 67108864UL);         // 8 MB (V transposed)
  float* beta = (float*)(ws + 75497472UL);     // 128 KB
  float* la_mean = (float*)(ws + 75628544UL);  // 32 B
  float* la_d = (float*)(ws + 75628800UL);     // 4 KB
  float2* cs = (float2*)(ws + 75632896UL);     // 1 MB rope table

  prep_kernel<<<9736, 256, 0, stream>>>(x, Wq, Wk, Wv, Wo, Wb, bb, alog,
                                        wqkvb, wob, xb, beta, la_mean, la_d,
                                        cs);
  qkv_gemm8p_kernel<<<256, 512, 0, stream>>>(xb, wqkvb, q, vt);
  rope_kernel<<<2048, 256, 0, stream>>>(q, kk, cs);
  attn_mfma_kernel<<<dim3(S_LEN / 64, NHEADS, BATCH), 256, 0, stream>>>(
      q, kk, vt, beta, la_mean, attnb);
  state_partial_kernel<<<dim3(16, 16), 256, 0, stream>>>(kk, vv, beta, la_d,
                                                         part);
  state_reduce_kernel<<<256, 256, 0, stream>>>(part, out + 8388608);
  oproj_kernel<<<256, 512, 0, stream>>>(attnb, wob, out);
}